// Round 1
// baseline (365.474 us; speedup 1.0000x reference)
//
#include <hip/hip_runtime.h>
#include <hip/hip_bf16.h>

// Problem dims (fixed by reference)
#define BB 8
#define NN 96
#define DD 512
#define EE 4
#define ROWS (BB * NN)          // 768
#define NCOLS_MSGS (2 * EE * DD) // 4096

// ---------------- ws layout (byte offsets) ----------------
// flags:   0      (16 B)          exist-encoding codes
// allmsgs: 1024   12,582,912 B    f32 [2*E*768][512]
// proj:    12,583,936  24,576 B   f32 [2*E*768]
// s1:      12,608,512   6,144 B   f32 [2*768]
// Acat:    12,614,656  4,718,592  f32 [768][1536]  (in_h | out_h | nodes)
// rn/z/Hpre alias allmsgs region (dead after attention):
//   rn:   1024, z: 1024+1572864, Hpre: 1024+3145728
#define WS_ALLMSGS 1024
#define WS_PROJ 12583936
#define WS_S1 12608512
#define WS_ACAT 12614656
#define WS_RN 1024
#define WS_Z (1024 + 1572864)
#define WS_HPRE (1024 + 3145728)

// ---------------- exist-encoding detection ----------------
// codes: 0 = u8/bool, 1 = int32, 2 = float32, 3 = int64
__global__ __launch_bounds__(256) void k_detect(const unsigned char* e0,
                                                const unsigned char* e1,
                                                int* flags, int nbytes) {
  __shared__ int mis, gt1, oddw;
  for (int arr = 0; arr < 2; ++arr) {
    const unsigned char* p = arr ? e1 : e0;
    if (threadIdx.x == 0) { mis = 0; gt1 = 0; oddw = 0; }
    __syncthreads();
    int lmis = 0, lgt = 0, lodd = 0;
    for (int i = threadIdx.x; i < nbytes; i += blockDim.x) {
      unsigned char v = p[i];
      if (v) {
        if (i & 3) lmis = 1;
        if (v > 1) lgt = 1;
        if ((i >> 2) & 1) lodd = 1;
      }
    }
    if (lmis) atomicOr(&mis, 1);
    if (lgt) atomicOr(&gt1, 1);
    if (lodd) atomicOr(&oddw, 1);
    __syncthreads();
    if (threadIdx.x == 0) {
      int code;
      if (mis) code = gt1 ? 2 : 0;
      else code = oddw ? 1 : 3;
      flags[arr] = code;
    }
    __syncthreads();
  }
}

__device__ __forceinline__ int get_exist(const void* p, int code, int idx) {
  switch (code) {
    case 0: return ((const unsigned char*)p)[idx] != 0;
    case 1: return ((const int*)p)[idx] != 0;
    case 2: return ((const float*)p)[idx] != 0.0f;
    default: return ((const long long*)p)[idx] != 0;
  }
}

// ---------------- copy nodes into Acat region 2 ----------------
__global__ __launch_bounds__(256) void k_copy_nodes(const float* __restrict__ nodes,
                                                    float* __restrict__ Acat) {
  int i = blockIdx.x * blockDim.x + threadIdx.x;
  if (i < ROWS * DD) {
    int row = i >> 9, h = i & 511;
    Acat[(size_t)row * 1536 + 1024 + h] = nodes[i];
  }
}

// ---------------- GEMM: all_msgs = nodes @ edges ----------------
// A: nodes [768,512], B: edges[(de)][k][hout], C: allmsgs [(de)*768+row][512]
__global__ __launch_bounds__(256) void k_gemm_msgs(const float* __restrict__ A,
                                                   const float* __restrict__ Edg,
                                                   float* __restrict__ C) {
  __shared__ float As[16][68];
  __shared__ float Bs[16][68];
  const int tid = threadIdx.x;
  const int tx = tid & 15, ty = tid >> 4;
  const int row0 = blockIdx.y * 64;
  const int col0 = blockIdx.x * 64;   // [0,4096)
  const int de = col0 >> 9;           // d*4+e
  const int h0 = col0 & 511;
  const float* Bp = Edg + (size_t)de * (DD * DD);
  const int ar = tid >> 2, ac4 = (tid & 3) * 4;
  const int brr = tid >> 4, bc4 = (tid & 15) * 4;
  float acc[4][4] = {};
  for (int k0 = 0; k0 < DD; k0 += 16) {
    float4 a4 = *(const float4*)(A + (size_t)(row0 + ar) * DD + k0 + ac4);
    As[ac4 + 0][ar] = a4.x; As[ac4 + 1][ar] = a4.y;
    As[ac4 + 2][ar] = a4.z; As[ac4 + 3][ar] = a4.w;
    *(float4*)&Bs[brr][bc4] =
        *(const float4*)(Bp + (size_t)(k0 + brr) * DD + h0 + bc4);
    __syncthreads();
#pragma unroll
    for (int kk = 0; kk < 16; ++kk) {
      float4 av = *(const float4*)&As[kk][ty * 4];
      float4 bv = *(const float4*)&Bs[kk][tx * 4];
      float ra[4] = {av.x, av.y, av.z, av.w};
      float rb[4] = {bv.x, bv.y, bv.z, bv.w};
#pragma unroll
      for (int i2 = 0; i2 < 4; ++i2)
#pragma unroll
        for (int j2 = 0; j2 < 4; ++j2)
          acc[i2][j2] = fmaf(ra[i2], rb[j2], acc[i2][j2]);
    }
    __syncthreads();
  }
#pragma unroll
  for (int i2 = 0; i2 < 4; ++i2) {
    int row = row0 + ty * 4 + i2;
    float4 o = {acc[i2][0], acc[i2][1], acc[i2][2], acc[i2][3]};
    *(float4*)(C + ((size_t)(de * ROWS + row)) * DD + h0 + tx * 4) = o;
  }
}

// ---------------- proj + s1 small reductions ----------------
// tasks 0..6143: proj[dir*3072 + e*768 + row] = allmsgs_row . Wa[dir][512:1024]
// tasks 6144..7679: s1[dir*768+row] = nodes_row . Wa[dir][0:512] + ba[dir]
__global__ __launch_bounds__(256) void k_projs1(const float* __restrict__ allmsgs,
                                                const float* __restrict__ nodes,
                                                const float* __restrict__ Wa_in,
                                                const float* __restrict__ ba_in,
                                                const float* __restrict__ Wa_out,
                                                const float* __restrict__ ba_out,
                                                float* __restrict__ proj,
                                                float* __restrict__ s1) {
  int w = blockIdx.x * 4 + (threadIdx.x >> 6);
  int lane = threadIdx.x & 63;
  const float* src;
  const float* wa;
  float bias = 0.f;
  float* dst;
  if (w < 2 * EE * ROWS) {
    int dir = w / (EE * ROWS);
    int rem = w % (EE * ROWS);
    src = allmsgs + ((size_t)(dir * EE + rem / ROWS) * ROWS + rem % ROWS) * DD;
    wa = (dir ? Wa_out : Wa_in) + DD;
    dst = proj + w;
  } else {
    int t = w - 2 * EE * ROWS;
    int dir = t / ROWS;
    int row = t % ROWS;
    src = nodes + (size_t)row * DD;
    wa = dir ? Wa_out : Wa_in;
    bias = dir ? ba_out[0] : ba_in[0];
    dst = s1 + t;
  }
  float acc = 0.f;
  for (int i = lane; i < DD; i += 64) acc = fmaf(src[i], wa[i], acc);
#pragma unroll
  for (int off = 32; off; off >>= 1) acc += __shfl_xor(acc, off);
  if (lane == 0) dst[0] = acc + bias;
}

// ---------------- attention: softmax over neighbors + weighted sum ----------------
// one block per (dir, b, i); writes Acat[row][dir*512 .. +512)
__global__ __launch_bounds__(256) void k_attn(const float* __restrict__ allmsgs,
                                              const float* __restrict__ proj,
                                              const float* __restrict__ s1,
                                              const int* __restrict__ adj_in,
                                              const int* __restrict__ adj_out,
                                              const void* exist_in,
                                              const void* exist_out,
                                              const int* __restrict__ flags,
                                              float* __restrict__ Acat) {
  __shared__ float s_w[NN];
  __shared__ int s_tj[NN];
  __shared__ int s_ex[NN];
  __shared__ float s_red[256];
  int blk = blockIdx.x;       // dir*768 + b*96 + i
  int dir = blk / ROWS;
  int row = blk % ROWS;       // b*96+i
  int b = row / NN;
  const int* adj = dir ? adj_out : adj_in;
  const void* ex = dir ? exist_out : exist_in;
  int code = flags[dir];
  int t = threadIdx.x;
  float s1v = s1[dir * ROWS + row];
  if (t < NN) {
    int idx = row * NN + t;   // (b*96+i)*96 + j
    int e_ = get_exist(ex, code, idx);
    int tj = adj[idx];
    s_ex[t] = e_;
    s_tj[t] = tj;
    float sc = -1e9f;
    if (e_) {
      float x = s1v + proj[dir * (EE * ROWS) + tj * ROWS + b * NN + t];
      sc = x >= 0.f ? x : 0.2f * x;
    }
    s_w[t] = sc;
  }
  __syncthreads();
  // block max over 96 scores
  float v = (t < NN) ? s_w[t] : -1e30f;
  s_red[t] = v;
  __syncthreads();
  for (int s = 128; s > 0; s >>= 1) {
    if (t < s) s_red[t] = fmaxf(s_red[t], s_red[t + s]);
    __syncthreads();
  }
  float mx = s_red[0];
  __syncthreads();
  float w = 0.f;
  if (t < NN && s_ex[t]) w = __expf(s_w[t] - mx);
  if (t < NN) s_w[t] = w;
  s_red[t] = w;
  __syncthreads();
  for (int s = 128; s > 0; s >>= 1) {
    if (t < s) s_red[t] += s_red[t + s];
    __syncthreads();
  }
  float inv = 1.f / s_red[0];
  // weighted sum over existing neighbors
  float acc0 = 0.f, acc1 = 0.f;
  int h0 = t, h1 = t + 256;
  for (int j = 0; j < NN; ++j) {
    if (s_ex[j]) {
      float wj = s_w[j];
      const float* rp =
          allmsgs + ((size_t)(dir * EE + s_tj[j]) * ROWS + b * NN + j) * DD;
      acc0 = fmaf(wj, rp[h0], acc0);
      acc1 = fmaf(wj, rp[h1], acc1);
    }
  }
  float* dst = Acat + (size_t)row * 1536 + dir * DD;
  dst[h0] = acc0 * inv;
  dst[h1] = acc1 * inv;
}

// ---------------- GEMM1: Acat[768,1536] @ {Wr|Wz|Wh[:1024]} with fused epilogue ----------------
__global__ __launch_bounds__(256) void k_gemm1(const float* __restrict__ Acat,
                                               const float* __restrict__ Wr,
                                               const float* __restrict__ Wz,
                                               const float* __restrict__ Wh,
                                               const float* __restrict__ br,
                                               const float* __restrict__ bz,
                                               const float* __restrict__ nodes,
                                               float* __restrict__ rn,
                                               float* __restrict__ zb,
                                               float* __restrict__ Hpre) {
  __shared__ float As[16][68];
  __shared__ float Bs[16][68];
  const int tid = threadIdx.x;
  const int tx = tid & 15, ty = tid >> 4;
  const int row0 = blockIdx.y * 64;
  const int col0 = blockIdx.x * 64;  // [0,1536)
  const int region = col0 >> 9;      // 0:Wr 1:Wz 2:Wh[:1024]
  const int c0 = col0 & 511;
  const float* Bsel = region == 0 ? Wr : (region == 1 ? Wz : Wh);
  const int Klim = (region == 2) ? 1024 : 1536;
  const int ar = tid >> 2, ac4 = (tid & 3) * 4;
  const int brr = tid >> 4, bc4 = (tid & 15) * 4;
  float acc[4][4] = {};
  for (int k0 = 0; k0 < Klim; k0 += 16) {
    float4 a4 = *(const float4*)(Acat + (size_t)(row0 + ar) * 1536 + k0 + ac4);
    As[ac4 + 0][ar] = a4.x; As[ac4 + 1][ar] = a4.y;
    As[ac4 + 2][ar] = a4.z; As[ac4 + 3][ar] = a4.w;
    *(float4*)&Bs[brr][bc4] =
        *(const float4*)(Bsel + (size_t)(k0 + brr) * DD + c0 + bc4);
    __syncthreads();
#pragma unroll
    for (int kk = 0; kk < 16; ++kk) {
      float4 av = *(const float4*)&As[kk][ty * 4];
      float4 bv = *(const float4*)&Bs[kk][tx * 4];
      float ra[4] = {av.x, av.y, av.z, av.w};
      float rb[4] = {bv.x, bv.y, bv.z, bv.w};
#pragma unroll
      for (int i2 = 0; i2 < 4; ++i2)
#pragma unroll
        for (int j2 = 0; j2 < 4; ++j2)
          acc[i2][j2] = fmaf(ra[i2], rb[j2], acc[i2][j2]);
    }
    __syncthreads();
  }
#pragma unroll
  for (int i2 = 0; i2 < 4; ++i2) {
    int row = row0 + ty * 4 + i2;
#pragma unroll
    for (int j2 = 0; j2 < 4; ++j2) {
      int c = c0 + tx * 4 + j2;
      float vv = acc[i2][j2];
      size_t o = (size_t)row * DD + c;
      if (region == 0) {
        float s = 1.f / (1.f + __expf(-(vv + br[c])));
        rn[o] = s * nodes[o];
      } else if (region == 1) {
        zb[o] = 1.f / (1.f + __expf(-(vv + bz[c])));
      } else {
        Hpre[o] = vv;
      }
    }
  }
}

// ---------------- GEMM2: rn @ Wh[1024:1536] + final gate ----------------
__global__ __launch_bounds__(256) void k_gemm2(const float* __restrict__ rn,
                                               const float* __restrict__ Wh,
                                               const float* __restrict__ bh,
                                               const float* __restrict__ Hpre,
                                               const float* __restrict__ zb,
                                               const float* __restrict__ nodes,
                                               float* __restrict__ out) {
  __shared__ float As[16][68];
  __shared__ float Bs[16][68];
  const int tid = threadIdx.x;
  const int tx = tid & 15, ty = tid >> 4;
  const int row0 = blockIdx.y * 64;
  const int col0 = blockIdx.x * 64;  // [0,512)
  const int ar = tid >> 2, ac4 = (tid & 3) * 4;
  const int brr = tid >> 4, bc4 = (tid & 15) * 4;
  float acc[4][4] = {};
  for (int k0 = 0; k0 < DD; k0 += 16) {
    float4 a4 = *(const float4*)(rn + (size_t)(row0 + ar) * DD + k0 + ac4);
    As[ac4 + 0][ar] = a4.x; As[ac4 + 1][ar] = a4.y;
    As[ac4 + 2][ar] = a4.z; As[ac4 + 3][ar] = a4.w;
    *(float4*)&Bs[brr][bc4] =
        *(const float4*)(Wh + (size_t)(1024 + k0 + brr) * DD + col0 + bc4);
    __syncthreads();
#pragma unroll
    for (int kk = 0; kk < 16; ++kk) {
      float4 av = *(const float4*)&As[kk][ty * 4];
      float4 bv = *(const float4*)&Bs[kk][tx * 4];
      float ra[4] = {av.x, av.y, av.z, av.w};
      float rb[4] = {bv.x, bv.y, bv.z, bv.w};
#pragma unroll
      for (int i2 = 0; i2 < 4; ++i2)
#pragma unroll
        for (int j2 = 0; j2 < 4; ++j2)
          acc[i2][j2] = fmaf(ra[i2], rb[j2], acc[i2][j2]);
    }
    __syncthreads();
  }
#pragma unroll
  for (int i2 = 0; i2 < 4; ++i2) {
    int row = row0 + ty * 4 + i2;
#pragma unroll
    for (int j2 = 0; j2 < 4; ++j2) {
      int c = col0 + tx * 4 + j2;
      size_t o = (size_t)row * DD + c;
      float hl = acc[i2][j2] + Hpre[o] + bh[c];
      float h = tanhf(hl);
      float zz = zb[o];
      float nd = nodes[o];
      out[o] = (1.f - zz) * nd + zz * h;
    }
  }
}

extern "C" void kernel_launch(void* const* d_in, const int* in_sizes, int n_in,
                              void* d_out, int out_size, void* d_ws, size_t ws_size,
                              hipStream_t stream) {
  const float* nodes = (const float*)d_in[0];
  const float* edges = (const float*)d_in[1];
  const int* adj_in = (const int*)d_in[2];
  const int* adj_out = (const int*)d_in[3];
  const void* exist_in = d_in[4];
  const void* exist_out = d_in[5];
  const float* Wa_in = (const float*)d_in[6];
  const float* ba_in = (const float*)d_in[7];
  const float* Wa_out = (const float*)d_in[8];
  const float* ba_out = (const float*)d_in[9];
  const float* Wr = (const float*)d_in[10];
  const float* br = (const float*)d_in[11];
  const float* Wz = (const float*)d_in[12];
  const float* bz = (const float*)d_in[13];
  const float* Wh = (const float*)d_in[14];
  const float* bh = (const float*)d_in[15];

  char* ws = (char*)d_ws;
  int* flags = (int*)ws;
  float* allmsgs = (float*)(ws + WS_ALLMSGS);
  float* proj = (float*)(ws + WS_PROJ);
  float* s1 = (float*)(ws + WS_S1);
  float* Acat = (float*)(ws + WS_ACAT);
  float* rn = (float*)(ws + WS_RN);
  float* zb = (float*)(ws + WS_Z);
  float* Hpre = (float*)(ws + WS_HPRE);
  float* out = (float*)d_out;

  k_detect<<<1, 256, 0, stream>>>((const unsigned char*)exist_in,
                                  (const unsigned char*)exist_out, flags,
                                  BB * NN * NN);
  k_copy_nodes<<<(ROWS * DD + 255) / 256, 256, 0, stream>>>(nodes, Acat);
  k_gemm_msgs<<<dim3(NCOLS_MSGS / 64, ROWS / 64), 256, 0, stream>>>(nodes, edges,
                                                                    allmsgs);
  k_projs1<<<(2 * EE * ROWS + 2 * ROWS) / 4, 256, 0, stream>>>(
      allmsgs, nodes, Wa_in, ba_in, Wa_out, ba_out, proj, s1);
  k_attn<<<2 * ROWS, 256, 0, stream>>>(allmsgs, proj, s1, adj_in, adj_out,
                                       exist_in, exist_out, flags, Acat);
  k_gemm1<<<dim3(1536 / 64, ROWS / 64), 256, 0, stream>>>(Acat, Wr, Wz, Wh, br,
                                                          bz, nodes, rn, zb, Hpre);
  k_gemm2<<<dim3(DD / 64, ROWS / 64), 256, 0, stream>>>(rn, Wh, bh, Hpre, zb,
                                                        nodes, out);
}

// Round 2
// 106.721 us; speedup vs baseline: 3.4246x; 3.4246x over previous
//
#include <hip/hip_runtime.h>
#include <hip/hip_bf16.h>

// Problem dims (fixed by reference)
#define BB 8
#define NN 96
#define DD 512
#define EE 4
#define ROWS (BB * NN)          // 768

typedef __attribute__((ext_vector_type(8))) short s8v;   // 8 bf16 = 4 VGPRs
typedef __attribute__((ext_vector_type(4))) short s4v;
typedef __attribute__((ext_vector_type(4))) float f32x4;

// ---------------- ws layout (byte offsets) ----------------
// flags_raw: 0..63 (zeroed each call via hipMemsetAsync)
// allmsgs f32 [8*768][512]: 1024 .. 12583936   (dead after k_attn)
//   aliased after attn:  rnH bf16 @1024 (786432)
//                        zb  f32 @787456 (1572864)
//                        Hpre f32 @2360320 (1572864)
//                        WT  bf16 @3933184 (4718592, ends 8651776)
// proj f32: 12583936 (24576)   s1 f32: 12608512 (6144)
// shared region @12614656 (4718592): edgesT bf16 (4194304) THEN Acat f32
//   (edgesT dead after k_gemm_msgs; Acat written after)
// total = 17333248 bytes (same footprint as round-1 which passed)
#define WS_ALLMSGS 1024
#define WS_RN      1024
#define WS_ZB      787456
#define WS_HPRE    2360320
#define WS_WT      3933184
#define WS_PROJ    12583936
#define WS_S1      12608512
#define WS_ACAT    12614656
#define WS_EDGEST  12614656

__device__ __forceinline__ short f2bf(float x) {   // RNE f32->bf16
  unsigned int u = __builtin_bit_cast(unsigned int, x);
  u += 0x7FFFu + ((u >> 16) & 1u);
  return (short)(u >> 16);
}

__device__ __forceinline__ f32x4 mfma16(s8v a, s8v b, f32x4 c) {
  asm("v_mfma_f32_16x16x32_bf16 %0, %1, %2, %0" : "+v"(c) : "v"(a), "v"(b));
  return c;
}

// ---------------- exist-encoding detection (grid-parallel) ----------------
// raw flags per dir: [mis, gt1, oddw]; code = mis ? (gt1?2:0) : (oddw?1:3)
// 0 = u8/bool, 1 = int32, 2 = float32, 3 = int64
__global__ __launch_bounds__(256) void k_detect(const unsigned int* __restrict__ e0,
                                                const unsigned int* __restrict__ e1,
                                                int* __restrict__ fr) {
  int gid = blockIdx.x * 256 + threadIdx.x;          // 0..36863 (2 arrays x 18432 dwords)
  int arr = gid >= 18432;                            // uniform per block (72*256=18432)
  int wi = arr ? gid - 18432 : gid;
  unsigned int v = (arr ? e1 : e0)[wi];
  int mis = 0, gt = 0, od = 0;
  if (v) {
    if (v & 0xFFFFFF00u) mis = 1;
    if (v & 0xFEFEFEFEu) gt = 1;
    if (wi & 1) od = 1;
  }
  unsigned long long bm = __ballot(mis), bg = __ballot(gt), bo = __ballot(od);
  if ((threadIdx.x & 63) == 0) {
    if (bm) atomicOr(&fr[arr * 3 + 0], 1);
    if (bg) atomicOr(&fr[arr * 3 + 1], 1);
    if (bo) atomicOr(&fr[arr * 3 + 2], 1);
  }
}

__device__ __forceinline__ int get_exist(const void* p, int code, int idx) {
  switch (code) {
    case 0: return ((const unsigned char*)p)[idx] != 0;
    case 1: return ((const int*)p)[idx] != 0;
    case 2: return ((const float*)p)[idx] != 0.0f;
    default: return ((const long long*)p)[idx] != 0;
  }
}

// ---------------- transpose kernels: f32 [R][512] -> bf16 [512][R] ----------------
__global__ __launch_bounds__(256) void k_tr_edges(const float* __restrict__ edges,
                                                  short* __restrict__ edgesT) {
  __shared__ float t[32][33];
  int de = blockIdx.z;
  const float* src = edges + (size_t)de * DD * DD;
  short* dst = edgesT + (size_t)de * DD * DD;
  int r0 = blockIdx.y * 32, c0 = blockIdx.x * 32;
  int row = threadIdx.x >> 3, c4 = (threadIdx.x & 7) * 4;
  float4 v = *(const float4*)(src + (size_t)(r0 + row) * DD + c0 + c4);
  t[row][c4] = v.x; t[row][c4 + 1] = v.y; t[row][c4 + 2] = v.z; t[row][c4 + 3] = v.w;
  __syncthreads();
  s4v o;
  o[0] = f2bf(t[c4 + 0][row]); o[1] = f2bf(t[c4 + 1][row]);
  o[2] = f2bf(t[c4 + 2][row]); o[3] = f2bf(t[c4 + 3][row]);
  *(s4v*)(dst + (size_t)(c0 + row) * DD + r0 + c4) = o;
}

// Wr/Wz/Wh [1536][512] -> WT[z][512][1536]
__global__ __launch_bounds__(256) void k_tr_w(const float* __restrict__ Wr,
                                              const float* __restrict__ Wz,
                                              const float* __restrict__ Wh,
                                              short* __restrict__ WT) {
  __shared__ float t[32][33];
  int z = blockIdx.z;
  const float* src = z == 0 ? Wr : (z == 1 ? Wz : Wh);
  short* dst = WT + (size_t)z * (512 * 1536);
  int r0 = blockIdx.y * 32, c0 = blockIdx.x * 32;   // r in [0,1536), c in [0,512)
  int row = threadIdx.x >> 3, c4 = (threadIdx.x & 7) * 4;
  float4 v = *(const float4*)(src + (size_t)(r0 + row) * DD + c0 + c4);
  t[row][c4] = v.x; t[row][c4 + 1] = v.y; t[row][c4 + 2] = v.z; t[row][c4 + 3] = v.w;
  __syncthreads();
  s4v o;
  o[0] = f2bf(t[c4 + 0][row]); o[1] = f2bf(t[c4 + 1][row]);
  o[2] = f2bf(t[c4 + 2][row]); o[3] = f2bf(t[c4 + 3][row]);
  *(s4v*)(dst + (size_t)(c0 + row) * 1536 + r0 + c4) = o;
}

// ---------------- staging + MFMA tile helpers ----------------
// LDS tile: 64 rows x 64 bf16, pitch 72 (pad +8 => 2-way bank aliasing, free)
__device__ __forceinline__ void stage_f32(const float* __restrict__ src, int pitch,
                                          short* lds, int tid) {
  int row = tid >> 2, cc = (tid & 3) * 16;
  const float* p = src + (size_t)row * pitch + cc;
  float4 v0 = *(const float4*)p;
  float4 v1 = *(const float4*)(p + 4);
  float4 v2 = *(const float4*)(p + 8);
  float4 v3 = *(const float4*)(p + 12);
  s8v h0, h1;
  h0[0] = f2bf(v0.x); h0[1] = f2bf(v0.y); h0[2] = f2bf(v0.z); h0[3] = f2bf(v0.w);
  h0[4] = f2bf(v1.x); h0[5] = f2bf(v1.y); h0[6] = f2bf(v1.z); h0[7] = f2bf(v1.w);
  h1[0] = f2bf(v2.x); h1[1] = f2bf(v2.y); h1[2] = f2bf(v2.z); h1[3] = f2bf(v2.w);
  h1[4] = f2bf(v3.x); h1[5] = f2bf(v3.y); h1[6] = f2bf(v3.z); h1[7] = f2bf(v3.w);
  *(s8v*)&lds[row * 72 + cc] = h0;
  *(s8v*)&lds[row * 72 + cc + 8] = h1;
}

__device__ __forceinline__ void stage_bf(const short* __restrict__ src, int pitch,
                                         short* lds, int tid) {
  int row = tid >> 2, cc = (tid & 3) * 16;
  const short* p = src + (size_t)row * pitch + cc;
  s8v h0 = *(const s8v*)p;
  s8v h1 = *(const s8v*)(p + 8);
  *(s8v*)&lds[row * 72 + cc] = h0;
  *(s8v*)&lds[row * 72 + cc + 8] = h1;
}

__device__ __forceinline__ void mfma_tile(const short* As, const short* Bs,
                                          int wr, int wc, int l, f32x4 acc[2][2]) {
  int lr = l & 15, lg = l >> 4;
#pragma unroll
  for (int ks = 0; ks < 64; ks += 32) {
    s8v a0 = *(const s8v*)&As[(wr + lr) * 72 + ks + 8 * lg];
    s8v a1 = *(const s8v*)&As[(wr + 16 + lr) * 72 + ks + 8 * lg];
    s8v b0 = *(const s8v*)&Bs[(wc + lr) * 72 + ks + 8 * lg];
    s8v b1 = *(const s8v*)&Bs[(wc + 16 + lr) * 72 + ks + 8 * lg];
    acc[0][0] = mfma16(a0, b0, acc[0][0]);
    acc[0][1] = mfma16(a0, b1, acc[0][1]);
    acc[1][0] = mfma16(a1, b0, acc[1][0]);
    acc[1][1] = mfma16(a1, b1, acc[1][1]);
  }
}

// ---------------- GEMM: allmsgs[de][m][n] = nodes[m][k] * edges[de][k][n] ----------------
__global__ __launch_bounds__(256) void k_gemm_msgs(const float* __restrict__ nodes,
                                                   const short* __restrict__ edgesT,
                                                   float* __restrict__ C) {
  __shared__ __align__(16) short As[64 * 72];
  __shared__ __align__(16) short Bs[64 * 72];
  int tid = threadIdx.x;
  int row0 = blockIdx.y * 64;
  int col0 = blockIdx.x * 64;        // [0,4096)
  int de = col0 >> 9, h0 = col0 & 511;
  const short* Bsrc = edgesT + (size_t)de * DD * DD + (size_t)h0 * DD;
  const float* Asrc = nodes + (size_t)row0 * DD;
  int w = tid >> 6, l = tid & 63;
  int wr = (w >> 1) * 32, wc = (w & 1) * 32;
  f32x4 acc[2][2] = {};
  for (int k0 = 0; k0 < DD; k0 += 64) {
    stage_f32(Asrc + k0, DD, As, tid);
    stage_bf(Bsrc + k0, DD, Bs, tid);
    __syncthreads();
    mfma_tile(As, Bs, wr, wc, l, acc);
    __syncthreads();
  }
  asm volatile("s_nop 7\n\ts_nop 7");   // MFMA->VALU writeback hazard guard
  int lr = l & 15, lg4 = (l >> 4) * 4;
#pragma unroll
  for (int fi = 0; fi < 2; ++fi)
#pragma unroll
    for (int fj = 0; fj < 2; ++fj) {
      f32x4 v = acc[fi][fj];
#pragma unroll
      for (int r = 0; r < 4; ++r) {
        int row = row0 + wr + fi * 16 + lg4 + r;
        int col = h0 + wc + fj * 16 + lr;
        C[((size_t)(de * ROWS + row)) * DD + col] = v[r];
      }
    }
}

// ---------------- proj + s1 small reductions (unchanged) ----------------
__global__ __launch_bounds__(256) void k_projs1(const float* __restrict__ allmsgs,
                                                const float* __restrict__ nodes,
                                                const float* __restrict__ Wa_in,
                                                const float* __restrict__ ba_in,
                                                const float* __restrict__ Wa_out,
                                                const float* __restrict__ ba_out,
                                                float* __restrict__ proj,
                                                float* __restrict__ s1) {
  int w = blockIdx.x * 4 + (threadIdx.x >> 6);
  int lane = threadIdx.x & 63;
  const float* src;
  const float* wa;
  float bias = 0.f;
  float* dst;
  if (w < 2 * EE * ROWS) {
    int dir = w / (EE * ROWS);
    int rem = w % (EE * ROWS);
    src = allmsgs + ((size_t)(dir * EE + rem / ROWS) * ROWS + rem % ROWS) * DD;
    wa = (dir ? Wa_out : Wa_in) + DD;
    dst = proj + w;
  } else {
    int t = w - 2 * EE * ROWS;
    int dir = t / ROWS;
    int row = t % ROWS;
    src = nodes + (size_t)row * DD;
    wa = dir ? Wa_out : Wa_in;
    bias = dir ? ba_out[0] : ba_in[0];
    dst = s1 + t;
  }
  float acc = 0.f;
  for (int i = lane; i < DD; i += 64) acc = fmaf(src[i], wa[i], acc);
#pragma unroll
  for (int off = 32; off; off >>= 1) acc += __shfl_xor(acc, off);
  if (lane == 0) dst[0] = acc + bias;
}

// ---------------- copy nodes into Acat region 2 ----------------
__global__ __launch_bounds__(256) void k_copy_nodes(const float* __restrict__ nodes,
                                                    float* __restrict__ Acat) {
  int i = blockIdx.x * blockDim.x + threadIdx.x;
  if (i < ROWS * DD) {
    int row = i >> 9, h = i & 511;
    Acat[(size_t)row * 1536 + 1024 + h] = nodes[i];
  }
}

// ---------------- attention ----------------
__global__ __launch_bounds__(256) void k_attn(const float* __restrict__ allmsgs,
                                              const float* __restrict__ proj,
                                              const float* __restrict__ s1,
                                              const int* __restrict__ adj_in,
                                              const int* __restrict__ adj_out,
                                              const void* exist_in,
                                              const void* exist_out,
                                              const int* __restrict__ fr,
                                              float* __restrict__ Acat) {
  __shared__ float s_w[NN];
  __shared__ int s_tj[NN];
  __shared__ int s_ex[NN];
  __shared__ float s_red[256];
  int blk = blockIdx.x;       // dir*768 + b*96 + i
  int dir = blk / ROWS;
  int row = blk % ROWS;
  int b = row / NN;
  const int* adj = dir ? adj_out : adj_in;
  const void* ex = dir ? exist_out : exist_in;
  int mis = fr[dir * 3 + 0], g1 = fr[dir * 3 + 1], od = fr[dir * 3 + 2];
  int code = mis ? (g1 ? 2 : 0) : (od ? 1 : 3);
  int t = threadIdx.x;
  float s1v = s1[dir * ROWS + row];
  if (t < NN) {
    int idx = row * NN + t;
    int e_ = get_exist(ex, code, idx);
    int tj = adj[idx];
    s_ex[t] = e_;
    s_tj[t] = tj;
    float sc = -1e9f;
    if (e_) {
      float x = s1v + proj[dir * (EE * ROWS) + tj * ROWS + b * NN + t];
      sc = x >= 0.f ? x : 0.2f * x;
    }
    s_w[t] = sc;
  }
  __syncthreads();
  float v = (t < NN) ? s_w[t] : -1e30f;
  s_red[t] = v;
  __syncthreads();
  for (int s = 128; s > 0; s >>= 1) {
    if (t < s) s_red[t] = fmaxf(s_red[t], s_red[t + s]);
    __syncthreads();
  }
  float mx = s_red[0];
  __syncthreads();
  float wgt = 0.f;
  if (t < NN && s_ex[t]) wgt = __expf(s_w[t] - mx);
  if (t < NN) s_w[t] = wgt;
  s_red[t] = wgt;
  __syncthreads();
  for (int s = 128; s > 0; s >>= 1) {
    if (t < s) s_red[t] += s_red[t + s];
    __syncthreads();
  }
  float inv = 1.f / s_red[0];
  float acc0 = 0.f, acc1 = 0.f;
  int h0 = t, h1 = t + 256;
  for (int j = 0; j < NN; ++j) {
    if (s_ex[j]) {
      float wj = s_w[j];
      const float* rp =
          allmsgs + ((size_t)(dir * EE + s_tj[j]) * ROWS + b * NN + j) * DD;
      acc0 = fmaf(wj, rp[h0], acc0);
      acc1 = fmaf(wj, rp[h1], acc1);
    }
  }
  float* dst = Acat + (size_t)row * 1536 + dir * DD;
  dst[h0] = acc0 * inv;
  dst[h1] = acc1 * inv;
}

// ---------------- GEMM1: Acat[768,1536] @ {WrT|WzT|WhT[:,:1024]} + epilogue ----------------
__global__ __launch_bounds__(256) void k_gemm1(const float* __restrict__ Acat,
                                               const short* __restrict__ WT,
                                               const float* __restrict__ br,
                                               const float* __restrict__ bz,
                                               const float* __restrict__ nodes,
                                               short* __restrict__ rnH,
                                               float* __restrict__ zb,
                                               float* __restrict__ Hpre) {
  __shared__ __align__(16) short As[64 * 72];
  __shared__ __align__(16) short Bs[64 * 72];
  int tid = threadIdx.x;
  int row0 = blockIdx.y * 64;
  int col0 = blockIdx.x * 64;           // [0,1536)
  int region = col0 >> 9, c0 = col0 & 511;
  int K = (region == 2) ? 1024 : 1536;
  const short* Bsrc = WT + (size_t)region * (512 * 1536) + (size_t)c0 * 1536;
  const float* Asrc = Acat + (size_t)row0 * 1536;
  int w = tid >> 6, l = tid & 63;
  int wr = (w >> 1) * 32, wc = (w & 1) * 32;
  f32x4 acc[2][2] = {};
  for (int k0 = 0; k0 < K; k0 += 64) {
    stage_f32(Asrc + k0, 1536, As, tid);
    stage_bf(Bsrc + k0, 1536, Bs, tid);
    __syncthreads();
    mfma_tile(As, Bs, wr, wc, l, acc);
    __syncthreads();
  }
  asm volatile("s_nop 7\n\ts_nop 7");
  int lr = l & 15, lg4 = (l >> 4) * 4;
#pragma unroll
  for (int fi = 0; fi < 2; ++fi)
#pragma unroll
    for (int fj = 0; fj < 2; ++fj) {
      f32x4 v = acc[fi][fj];
#pragma unroll
      for (int r = 0; r < 4; ++r) {
        int row = row0 + wr + fi * 16 + lg4 + r;
        int c = c0 + wc + fj * 16 + lr;
        float vv = v[r];
        size_t o = (size_t)row * DD + c;
        if (region == 0) {
          float s = 1.f / (1.f + __expf(-(vv + br[c])));
          rnH[o] = f2bf(s * nodes[o]);
        } else if (region == 1) {
          zb[o] = 1.f / (1.f + __expf(-(vv + bz[c])));
        } else {
          Hpre[o] = vv;
        }
      }
    }
}

// ---------------- GEMM2: rn @ WhT[:,1024:] + final gate ----------------
__global__ __launch_bounds__(256) void k_gemm2(const short* __restrict__ rnH,
                                               const short* __restrict__ WT,
                                               const float* __restrict__ bh,
                                               const float* __restrict__ Hpre,
                                               const float* __restrict__ zb,
                                               const float* __restrict__ nodes,
                                               float* __restrict__ out) {
  __shared__ __align__(16) short As[64 * 72];
  __shared__ __align__(16) short Bs[64 * 72];
  int tid = threadIdx.x;
  int row0 = blockIdx.y * 64;
  int col0 = blockIdx.x * 64;           // [0,512)
  const short* Bsrc = WT + (size_t)2 * (512 * 1536) + (size_t)col0 * 1536 + 1024;
  const short* Asrc = rnH + (size_t)row0 * DD;
  int w = tid >> 6, l = tid & 63;
  int wr = (w >> 1) * 32, wc = (w & 1) * 32;
  f32x4 acc[2][2] = {};
  for (int k0 = 0; k0 < DD; k0 += 64) {
    stage_bf(Asrc + k0, DD, As, tid);
    stage_bf(Bsrc + k0, 1536, Bs, tid);
    __syncthreads();
    mfma_tile(As, Bs, wr, wc, l, acc);
    __syncthreads();
  }
  asm volatile("s_nop 7\n\ts_nop 7");
  int lr = l & 15, lg4 = (l >> 4) * 4;
#pragma unroll
  for (int fi = 0; fi < 2; ++fi)
#pragma unroll
    for (int fj = 0; fj < 2; ++fj) {
      f32x4 v = acc[fi][fj];
#pragma unroll
      for (int r = 0; r < 4; ++r) {
        int row = row0 + wr + fi * 16 + lg4 + r;
        int c = col0 + wc + fj * 16 + lr;
        size_t o = (size_t)row * DD + c;
        float h = tanhf(v[r] + Hpre[o] + bh[c]);
        float zz = zb[o];
        float nd = nodes[o];
        out[o] = (1.f - zz) * nd + zz * h;
      }
    }
}

extern "C" void kernel_launch(void* const* d_in, const int* in_sizes, int n_in,
                              void* d_out, int out_size, void* d_ws, size_t ws_size,
                              hipStream_t stream) {
  const float* nodes = (const float*)d_in[0];
  const float* edges = (const float*)d_in[1];
  const int* adj_in = (const int*)d_in[2];
  const int* adj_out = (const int*)d_in[3];
  const void* exist_in = d_in[4];
  const void* exist_out = d_in[5];
  const float* Wa_in = (const float*)d_in[6];
  const float* ba_in = (const float*)d_in[7];
  const float* Wa_out = (const float*)d_in[8];
  const float* ba_out = (const float*)d_in[9];
  const float* Wr = (const float*)d_in[10];
  const float* br = (const float*)d_in[11];
  const float* Wz = (const float*)d_in[12];
  const float* bz = (const float*)d_in[13];
  const float* Wh = (const float*)d_in[14];
  const float* bh = (const float*)d_in[15];

  char* ws = (char*)d_ws;
  int* flags = (int*)ws;
  float* allmsgs = (float*)(ws + WS_ALLMSGS);
  short* rnH = (short*)(ws + WS_RN);
  float* zb = (float*)(ws + WS_ZB);
  float* Hpre = (float*)(ws + WS_HPRE);
  short* WT = (short*)(ws + WS_WT);
  float* proj = (float*)(ws + WS_PROJ);
  float* s1 = (float*)(ws + WS_S1);
  float* Acat = (float*)(ws + WS_ACAT);
  short* edgesT = (short*)(ws + WS_EDGEST);
  float* out = (float*)d_out;

  hipMemsetAsync(ws, 0, 64, stream);
  k_detect<<<144, 256, 0, stream>>>((const unsigned int*)exist_in,
                                    (const unsigned int*)exist_out, flags);
  k_tr_edges<<<dim3(16, 16, 8), 256, 0, stream>>>(edges, edgesT);
  k_gemm_msgs<<<dim3(64, 12), 256, 0, stream>>>(nodes, edgesT, allmsgs);
  k_projs1<<<(2 * EE * ROWS + 2 * ROWS) / 4, 256, 0, stream>>>(
      allmsgs, nodes, Wa_in, ba_in, Wa_out, ba_out, proj, s1);
  // Acat overwrites edgesT region: must launch after k_gemm_msgs (stream-ordered)
  k_copy_nodes<<<(ROWS * DD + 255) / 256, 256, 0, stream>>>(nodes, Acat);
  k_attn<<<2 * ROWS, 256, 0, stream>>>(allmsgs, proj, s1, adj_in, adj_out,
                                       exist_in, exist_out, flags, Acat);
  // WT overwrites (part of) allmsgs: after attn (last reader of allmsgs)
  k_tr_w<<<dim3(16, 48, 3), 256, 0, stream>>>(Wr, Wz, Wh, WT);
  k_gemm1<<<dim3(24, 12), 256, 0, stream>>>(Acat, WT, br, bz, nodes, rnH, zb, Hpre);
  k_gemm2<<<dim3(8, 12), 256, 0, stream>>>(rnH, WT, bh, Hpre, zb, nodes, out);
}

// Round 3
// 95.816 us; speedup vs baseline: 3.8143x; 1.1138x over previous
//
#include <hip/hip_runtime.h>
#include <hip/hip_bf16.h>

// Problem dims (fixed by reference)
#define BB 8
#define NN 96
#define DD 512
#define EE 4
#define ROWS (BB * NN)          // 768

typedef __attribute__((ext_vector_type(8))) short s8v;   // 8 bf16 = 4 VGPRs
typedef __attribute__((ext_vector_type(4))) short s4v;
typedef __attribute__((ext_vector_type(4))) float f32x4;

// ---------------- ws layout (byte offsets) ----------------
// flags: 0..63 (written directly by k_detect, no pre-zero needed)
// allmsgs f32 [8*768][512]: 1024 .. 12583936   (dead after k_attn)
//   aliased after attn:  rnH bf16 @1024 (786432)
//                        zb  f32 @787456 (1572864)
//                        Hpre f32 @2360320 (1572864)
//                        WT  bf16 @3933184 (4718592, ends 8651776)
// proj f32: 12583936 (24576)   s1 f32: 12608512 (6144)
// shared region @12614656 (4718592): edgesT bf16 (4194304) THEN Acat f32
// total = 17333248 bytes (proven footprint)
#define WS_ALLMSGS 1024
#define WS_RN      1024
#define WS_ZB      787456
#define WS_HPRE    2360320
#define WS_WT      3933184
#define WS_PROJ    12583936
#define WS_S1      12608512
#define WS_ACAT    12614656
#define WS_EDGEST  12614656

__device__ __forceinline__ short f2bf(float x) {   // RNE f32->bf16
  unsigned int u = __builtin_bit_cast(unsigned int, x);
  u += 0x7FFFu + ((u >> 16) & 1u);
  return (short)(u >> 16);
}

__device__ __forceinline__ f32x4 mfma16(s8v a, s8v b, f32x4 c) {
  asm("v_mfma_f32_16x16x32_bf16 %0, %1, %2, %0" : "+v"(c) : "v"(a), "v"(b));
  return c;
}

// ---------------- exist-encoding detection ----------------
// codes: 0 = u8/bool, 1 = int32, 2 = float32, 3 = int64
// One block per array; LDS-only reduction; writes final code. No pre-zero.
__global__ __launch_bounds__(1024) void k_detect(const uint4* __restrict__ e0,
                                                 const uint4* __restrict__ e1,
                                                 int* __restrict__ flags) {
  __shared__ int red[3];
  int t = threadIdx.x;
  int arr = blockIdx.x;
  if (t < 3) red[t] = 0;
  __syncthreads();
  const uint4* p = arr ? e1 : e0;
  int mis = 0, gt = 0, od = 0;
  for (int i = t; i < 4608; i += 1024) {    // first 73728 bytes (prefix is enough; 10% density)
    uint4 v = p[i];
    unsigned any = v.x | v.y | v.z | v.w;
    if (any) {
      if (any & 0xFFFFFF00u) mis = 1;       // nonzero byte off 4-alignment -> u8 or f32
      if (any & 0xFEFEFEFEu) gt = 1;        // byte value >1 -> f32
      if (v.y | v.w) od = 1;                // odd dword nonzero -> i32 (vs i64)
    }
  }
  if (mis) atomicOr(&red[0], 1);
  if (gt) atomicOr(&red[1], 1);
  if (od) atomicOr(&red[2], 1);
  __syncthreads();
  if (t == 0) flags[arr] = red[0] ? (red[1] ? 2 : 0) : (red[2] ? 1 : 3);
}

__device__ __forceinline__ int get_exist(const void* p, int code, int idx) {
  switch (code) {
    case 0: return ((const unsigned char*)p)[idx] != 0;
    case 1: return ((const int*)p)[idx] != 0;
    case 2: return ((const float*)p)[idx] != 0.0f;
    default: return ((const long long*)p)[idx] != 0;
  }
}

// ---------------- transpose kernels: f32 [R][512] -> bf16 [512][R] ----------------
__global__ __launch_bounds__(256) void k_tr_edges(const float* __restrict__ edges,
                                                  short* __restrict__ edgesT) {
  __shared__ float t[32][33];
  int de = blockIdx.z;
  const float* src = edges + (size_t)de * DD * DD;
  short* dst = edgesT + (size_t)de * DD * DD;
  int r0 = blockIdx.y * 32, c0 = blockIdx.x * 32;
  int row = threadIdx.x >> 3, c4 = (threadIdx.x & 7) * 4;
  float4 v = *(const float4*)(src + (size_t)(r0 + row) * DD + c0 + c4);
  t[row][c4] = v.x; t[row][c4 + 1] = v.y; t[row][c4 + 2] = v.z; t[row][c4 + 3] = v.w;
  __syncthreads();
  s4v o;
  o[0] = f2bf(t[c4 + 0][row]); o[1] = f2bf(t[c4 + 1][row]);
  o[2] = f2bf(t[c4 + 2][row]); o[3] = f2bf(t[c4 + 3][row]);
  *(s4v*)(dst + (size_t)(c0 + row) * DD + r0 + c4) = o;
}

// Wr/Wz/Wh [1536][512] -> WT[z][512][1536]
__global__ __launch_bounds__(256) void k_tr_w(const float* __restrict__ Wr,
                                              const float* __restrict__ Wz,
                                              const float* __restrict__ Wh,
                                              short* __restrict__ WT) {
  __shared__ float t[32][33];
  int z = blockIdx.z;
  const float* src = z == 0 ? Wr : (z == 1 ? Wz : Wh);
  short* dst = WT + (size_t)z * (512 * 1536);
  int r0 = blockIdx.y * 32, c0 = blockIdx.x * 32;   // r in [0,1536), c in [0,512)
  int row = threadIdx.x >> 3, c4 = (threadIdx.x & 7) * 4;
  float4 v = *(const float4*)(src + (size_t)(r0 + row) * DD + c0 + c4);
  t[row][c4] = v.x; t[row][c4 + 1] = v.y; t[row][c4 + 2] = v.z; t[row][c4 + 3] = v.w;
  __syncthreads();
  s4v o;
  o[0] = f2bf(t[c4 + 0][row]); o[1] = f2bf(t[c4 + 1][row]);
  o[2] = f2bf(t[c4 + 2][row]); o[3] = f2bf(t[c4 + 3][row]);
  *(s4v*)(dst + (size_t)(c0 + row) * 1536 + r0 + c4) = o;
}

// ---------------- staging + MFMA tile helpers ----------------
// LDS tile: 64 rows x 64 bf16, pitch 72 (pad +8 => 2-way bank aliasing, free)
__device__ __forceinline__ void stage_f32(const float* __restrict__ src, int pitch,
                                          short* lds, int tid) {
  int row = tid >> 2, cc = (tid & 3) * 16;
  const float* p = src + (size_t)row * pitch + cc;
  float4 v0 = *(const float4*)p;
  float4 v1 = *(const float4*)(p + 4);
  float4 v2 = *(const float4*)(p + 8);
  float4 v3 = *(const float4*)(p + 12);
  s8v h0, h1;
  h0[0] = f2bf(v0.x); h0[1] = f2bf(v0.y); h0[2] = f2bf(v0.z); h0[3] = f2bf(v0.w);
  h0[4] = f2bf(v1.x); h0[5] = f2bf(v1.y); h0[6] = f2bf(v1.z); h0[7] = f2bf(v1.w);
  h1[0] = f2bf(v2.x); h1[1] = f2bf(v2.y); h1[2] = f2bf(v2.z); h1[3] = f2bf(v2.w);
  h1[4] = f2bf(v3.x); h1[5] = f2bf(v3.y); h1[6] = f2bf(v3.z); h1[7] = f2bf(v3.w);
  *(s8v*)&lds[row * 72 + cc] = h0;
  *(s8v*)&lds[row * 72 + cc + 8] = h1;
}

__device__ __forceinline__ void stage_bf(const short* __restrict__ src, int pitch,
                                         short* lds, int tid) {
  int row = tid >> 2, cc = (tid & 3) * 16;
  const short* p = src + (size_t)row * pitch + cc;
  s8v h0 = *(const s8v*)p;
  s8v h1 = *(const s8v*)(p + 8);
  *(s8v*)&lds[row * 72 + cc] = h0;
  *(s8v*)&lds[row * 72 + cc + 8] = h1;
}

__device__ __forceinline__ void mfma_tile(const short* As, const short* Bs,
                                          int wr, int wc, int l, f32x4 acc[2][2]) {
  int lr = l & 15, lg = l >> 4;
#pragma unroll
  for (int ks = 0; ks < 64; ks += 32) {
    s8v a0 = *(const s8v*)&As[(wr + lr) * 72 + ks + 8 * lg];
    s8v a1 = *(const s8v*)&As[(wr + 16 + lr) * 72 + ks + 8 * lg];
    s8v b0 = *(const s8v*)&Bs[(wc + lr) * 72 + ks + 8 * lg];
    s8v b1 = *(const s8v*)&Bs[(wc + 16 + lr) * 72 + ks + 8 * lg];
    acc[0][0] = mfma16(a0, b0, acc[0][0]);
    acc[0][1] = mfma16(a0, b1, acc[0][1]);
    acc[1][0] = mfma16(a1, b0, acc[1][0]);
    acc[1][1] = mfma16(a1, b1, acc[1][1]);
  }
}

// ---------------- GEMM: allmsgs[de][m][n] = nodes[m][k] * edges[de][k][n] ----------------
__global__ __launch_bounds__(256) void k_gemm_msgs(const float* __restrict__ nodes,
                                                   const short* __restrict__ edgesT,
                                                   float* __restrict__ C) {
  __shared__ __align__(16) short As[64 * 72];
  __shared__ __align__(16) short Bs[64 * 72];
  int tid = threadIdx.x;
  int row0 = blockIdx.y * 64;
  int col0 = blockIdx.x * 64;        // [0,4096)
  int de = col0 >> 9, h0 = col0 & 511;
  const short* Bsrc = edgesT + (size_t)de * DD * DD + (size_t)h0 * DD;
  const float* Asrc = nodes + (size_t)row0 * DD;
  int w = tid >> 6, l = tid & 63;
  int wr = (w >> 1) * 32, wc = (w & 1) * 32;
  f32x4 acc[2][2] = {};
  for (int k0 = 0; k0 < DD; k0 += 64) {
    stage_f32(Asrc + k0, DD, As, tid);
    stage_bf(Bsrc + k0, DD, Bs, tid);
    __syncthreads();
    mfma_tile(As, Bs, wr, wc, l, acc);
    __syncthreads();
  }
  asm volatile("s_nop 7\n\ts_nop 7");   // MFMA->VALU writeback hazard guard
  int lr = l & 15, lg4 = (l >> 4) * 4;
#pragma unroll
  for (int fi = 0; fi < 2; ++fi)
#pragma unroll
    for (int fj = 0; fj < 2; ++fj) {
      f32x4 v = acc[fi][fj];
#pragma unroll
      for (int r = 0; r < 4; ++r) {
        int row = row0 + wr + fi * 16 + lg4 + r;
        int col = h0 + wc + fj * 16 + lr;
        C[((size_t)(de * ROWS + row)) * DD + col] = v[r];
      }
    }
}

// ---------------- proj + s1 small reductions ----------------
__global__ __launch_bounds__(256) void k_projs1(const float* __restrict__ allmsgs,
                                                const float* __restrict__ nodes,
                                                const float* __restrict__ Wa_in,
                                                const float* __restrict__ ba_in,
                                                const float* __restrict__ Wa_out,
                                                const float* __restrict__ ba_out,
                                                float* __restrict__ proj,
                                                float* __restrict__ s1) {
  int w = blockIdx.x * 4 + (threadIdx.x >> 6);
  int lane = threadIdx.x & 63;
  const float* src;
  const float* wa;
  float bias = 0.f;
  float* dst;
  if (w < 2 * EE * ROWS) {
    int dir = w / (EE * ROWS);
    int rem = w % (EE * ROWS);
    src = allmsgs + ((size_t)(dir * EE + rem / ROWS) * ROWS + rem % ROWS) * DD;
    wa = (dir ? Wa_out : Wa_in) + DD;
    dst = proj + w;
  } else {
    int t = w - 2 * EE * ROWS;
    int dir = t / ROWS;
    int row = t % ROWS;
    src = nodes + (size_t)row * DD;
    wa = dir ? Wa_out : Wa_in;
    bias = dir ? ba_out[0] : ba_in[0];
    dst = s1 + t;
  }
  float acc = 0.f;
  for (int i = lane; i < DD; i += 64) acc = fmaf(src[i], wa[i], acc);
#pragma unroll
  for (int off = 32; off; off >>= 1) acc += __shfl_xor(acc, off);
  if (lane == 0) dst[0] = acc + bias;
}

// ---------------- attention (+ fused nodes->Acat copy for dir==0) ----------------
__global__ __launch_bounds__(256) void k_attn(const float* __restrict__ allmsgs,
                                              const float* __restrict__ proj,
                                              const float* __restrict__ s1,
                                              const int* __restrict__ adj_in,
                                              const int* __restrict__ adj_out,
                                              const void* exist_in,
                                              const void* exist_out,
                                              const int* __restrict__ fr,
                                              const float* __restrict__ nodes,
                                              float* __restrict__ Acat) {
  __shared__ float s_w[NN];
  __shared__ int s_tj[NN];
  __shared__ int s_ex[NN];
  __shared__ float s_red[256];
  int blk = blockIdx.x;       // dir*768 + b*96 + i
  int dir = blk / ROWS;
  int row = blk % ROWS;
  int b = row / NN;
  const int* adj = dir ? adj_out : adj_in;
  const void* ex = dir ? exist_out : exist_in;
  int code = fr[dir];
  int t = threadIdx.x;
  int h0 = t, h1 = t + 256;
  // fused: copy nodes into Acat third region (once, via dir==0 blocks)
  if (dir == 0) {
    float* dn = Acat + (size_t)row * 1536 + 1024;
    dn[h0] = nodes[(size_t)row * DD + h0];
    dn[h1] = nodes[(size_t)row * DD + h1];
  }
  float s1v = s1[dir * ROWS + row];
  if (t < NN) {
    int idx = row * NN + t;
    int e_ = get_exist(ex, code, idx);
    int tj = adj[idx];
    s_ex[t] = e_;
    s_tj[t] = tj;
    float sc = -1e9f;
    if (e_) {
      float x = s1v + proj[dir * (EE * ROWS) + tj * ROWS + b * NN + t];
      sc = x >= 0.f ? x : 0.2f * x;
    }
    s_w[t] = sc;
  }
  __syncthreads();
  float v = (t < NN) ? s_w[t] : -1e30f;
  s_red[t] = v;
  __syncthreads();
  for (int s = 128; s > 0; s >>= 1) {
    if (t < s) s_red[t] = fmaxf(s_red[t], s_red[t + s]);
    __syncthreads();
  }
  float mx = s_red[0];
  __syncthreads();
  float wgt = 0.f;
  if (t < NN && s_ex[t]) wgt = __expf(s_w[t] - mx);
  if (t < NN) s_w[t] = wgt;
  s_red[t] = wgt;
  __syncthreads();
  for (int s = 128; s > 0; s >>= 1) {
    if (t < s) s_red[t] += s_red[t + s];
    __syncthreads();
  }
  float inv = 1.f / s_red[0];
  float acc0 = 0.f, acc1 = 0.f;
  for (int j = 0; j < NN; ++j) {
    if (s_ex[j]) {
      float wj = s_w[j];
      const float* rp =
          allmsgs + ((size_t)(dir * EE + s_tj[j]) * ROWS + b * NN + j) * DD;
      acc0 = fmaf(wj, rp[h0], acc0);
      acc1 = fmaf(wj, rp[h1], acc1);
    }
  }
  float* dst = Acat + (size_t)row * 1536 + dir * DD;
  dst[h0] = acc0 * inv;
  dst[h1] = acc1 * inv;
}

// ---------------- GEMM1: Acat[768,1536] @ {WrT|WzT|WhT[:,:1024]} + epilogue ----------------
__global__ __launch_bounds__(256) void k_gemm1(const float* __restrict__ Acat,
                                               const short* __restrict__ WT,
                                               const float* __restrict__ br,
                                               const float* __restrict__ bz,
                                               const float* __restrict__ nodes,
                                               short* __restrict__ rnH,
                                               float* __restrict__ zb,
                                               float* __restrict__ Hpre) {
  __shared__ __align__(16) short As[64 * 72];
  __shared__ __align__(16) short Bs[64 * 72];
  int tid = threadIdx.x;
  int row0 = blockIdx.y * 64;
  int col0 = blockIdx.x * 64;           // [0,1536)
  int region = col0 >> 9, c0 = col0 & 511;
  int K = (region == 2) ? 1024 : 1536;
  const short* Bsrc = WT + (size_t)region * (512 * 1536) + (size_t)c0 * 1536;
  const float* Asrc = Acat + (size_t)row0 * 1536;
  int w = tid >> 6, l = tid & 63;
  int wr = (w >> 1) * 32, wc = (w & 1) * 32;
  f32x4 acc[2][2] = {};
  for (int k0 = 0; k0 < K; k0 += 64) {
    stage_f32(Asrc + k0, 1536, As, tid);
    stage_bf(Bsrc + k0, 1536, Bs, tid);
    __syncthreads();
    mfma_tile(As, Bs, wr, wc, l, acc);
    __syncthreads();
  }
  asm volatile("s_nop 7\n\ts_nop 7");
  int lr = l & 15, lg4 = (l >> 4) * 4;
#pragma unroll
  for (int fi = 0; fi < 2; ++fi)
#pragma unroll
    for (int fj = 0; fj < 2; ++fj) {
      f32x4 v = acc[fi][fj];
#pragma unroll
      for (int r = 0; r < 4; ++r) {
        int row = row0 + wr + fi * 16 + lg4 + r;
        int c = c0 + wc + fj * 16 + lr;
        float vv = v[r];
        size_t o = (size_t)row * DD + c;
        if (region == 0) {
          float s = 1.f / (1.f + __expf(-(vv + br[c])));
          rnH[o] = f2bf(s * nodes[o]);
        } else if (region == 1) {
          zb[o] = 1.f / (1.f + __expf(-(vv + bz[c])));
        } else {
          Hpre[o] = vv;
        }
      }
    }
}

// ---------------- GEMM2: rn @ WhT[:,1024:] + final gate ----------------
__global__ __launch_bounds__(256) void k_gemm2(const short* __restrict__ rnH,
                                               const short* __restrict__ WT,
                                               const float* __restrict__ bh,
                                               const float* __restrict__ Hpre,
                                               const float* __restrict__ zb,
                                               const float* __restrict__ nodes,
                                               float* __restrict__ out) {
  __shared__ __align__(16) short As[64 * 72];
  __shared__ __align__(16) short Bs[64 * 72];
  int tid = threadIdx.x;
  int row0 = blockIdx.y * 64;
  int col0 = blockIdx.x * 64;           // [0,512)
  const short* Bsrc = WT + (size_t)2 * (512 * 1536) + (size_t)col0 * 1536 + 1024;
  const short* Asrc = rnH + (size_t)row0 * DD;
  int w = tid >> 6, l = tid & 63;
  int wr = (w >> 1) * 32, wc = (w & 1) * 32;
  f32x4 acc[2][2] = {};
  for (int k0 = 0; k0 < DD; k0 += 64) {
    stage_bf(Asrc + k0, DD, As, tid);
    stage_bf(Bsrc + k0, 1536, Bs, tid);
    __syncthreads();
    mfma_tile(As, Bs, wr, wc, l, acc);
    __syncthreads();
  }
  asm volatile("s_nop 7\n\ts_nop 7");
  int lr = l & 15, lg4 = (l >> 4) * 4;
#pragma unroll
  for (int fi = 0; fi < 2; ++fi)
#pragma unroll
    for (int fj = 0; fj < 2; ++fj) {
      f32x4 v = acc[fi][fj];
#pragma unroll
      for (int r = 0; r < 4; ++r) {
        int row = row0 + wr + fi * 16 + lg4 + r;
        int c = col0 + wc + fj * 16 + lr;
        size_t o = (size_t)row * DD + c;
        float h = tanhf(v[r] + Hpre[o] + bh[c]);
        float zz = zb[o];
        float nd = nodes[o];
        out[o] = (1.f - zz) * nd + zz * h;
      }
    }
}

extern "C" void kernel_launch(void* const* d_in, const int* in_sizes, int n_in,
                              void* d_out, int out_size, void* d_ws, size_t ws_size,
                              hipStream_t stream) {
  const float* nodes = (const float*)d_in[0];
  const float* edges = (const float*)d_in[1];
  const int* adj_in = (const int*)d_in[2];
  const int* adj_out = (const int*)d_in[3];
  const void* exist_in = d_in[4];
  const void* exist_out = d_in[5];
  const float* Wa_in = (const float*)d_in[6];
  const float* ba_in = (const float*)d_in[7];
  const float* Wa_out = (const float*)d_in[8];
  const float* ba_out = (const float*)d_in[9];
  const float* Wr = (const float*)d_in[10];
  const float* br = (const float*)d_in[11];
  const float* Wz = (const float*)d_in[12];
  const float* bz = (const float*)d_in[13];
  const float* Wh = (const float*)d_in[14];
  const float* bh = (const float*)d_in[15];

  char* ws = (char*)d_ws;
  int* flags = (int*)ws;
  float* allmsgs = (float*)(ws + WS_ALLMSGS);
  short* rnH = (short*)(ws + WS_RN);
  float* zb = (float*)(ws + WS_ZB);
  float* Hpre = (float*)(ws + WS_HPRE);
  short* WT = (short*)(ws + WS_WT);
  float* proj = (float*)(ws + WS_PROJ);
  float* s1 = (float*)(ws + WS_S1);
  float* Acat = (float*)(ws + WS_ACAT);
  short* edgesT = (short*)(ws + WS_EDGEST);
  float* out = (float*)d_out;

  k_detect<<<2, 1024, 0, stream>>>((const uint4*)exist_in,
                                   (const uint4*)exist_out, flags);
  k_tr_edges<<<dim3(16, 16, 8), 256, 0, stream>>>(edges, edgesT);
  k_gemm_msgs<<<dim3(64, 12), 256, 0, stream>>>(nodes, edgesT, allmsgs);
  k_projs1<<<(2 * EE * ROWS + 2 * ROWS) / 4, 256, 0, stream>>>(
      allmsgs, nodes, Wa_in, ba_in, Wa_out, ba_out, proj, s1);
  k_attn<<<2 * ROWS, 256, 0, stream>>>(allmsgs, proj, s1, adj_in, adj_out,
                                       exist_in, exist_out, flags, nodes, Acat);
  // WT overwrites (part of) allmsgs: after attn (last reader of allmsgs)
  k_tr_w<<<dim3(16, 48, 3), 256, 0, stream>>>(Wr, Wz, Wh, WT);
  k_gemm1<<<dim3(24, 12), 256, 0, stream>>>(Acat, WT, br, bz, nodes, rnH, zb, Hpre);
  k_gemm2<<<dim3(8, 12), 256, 0, stream>>>(rnH, WT, bh, Hpre, zb, nodes, out);
}

// Round 4
// 80.001 us; speedup vs baseline: 4.5684x; 1.1977x over previous
//
#include <hip/hip_runtime.h>
#include <hip/hip_bf16.h>

// Problem dims (fixed by reference)
#define BB 8
#define NN 96
#define DD 512
#define EE 4
#define ROWS (BB * NN)          // 768

typedef __attribute__((ext_vector_type(8))) short s8v;   // 8 bf16 = 4 VGPRs
typedef __attribute__((ext_vector_type(4))) short s4v;
typedef __attribute__((ext_vector_type(4))) float f32x4;

// ---------------- ws layout (flat, no aliasing; ws = 256 MiB) ----------------
#define WS_ALLMSGS 1024                 // bf16 [8*768][512]  = 6,291,456
#define WS_PROJ    6292480              // f32  [6144]        = 24,576
#define WS_ACAT    6317056              // bf16 [768][1536]   = 2,359,296
#define WS_EDGEST  8676352              // bf16 [8][512][512] = 4,194,304
#define WS_WT      12870656             // bf16 [3][512][1536]= 4,718,592
#define WS_RN      17589248             // bf16 [768][512]    = 786,432
#define WS_ZB      18375680             // f32  [768][512]    = 1,572,864
#define WS_HPRE    19948544             // f32  [768][512]    = 1,572,864  (ends ~21.5MB)

__device__ __forceinline__ short f2bf(float x) {   // RNE f32->bf16
  unsigned int u = __builtin_bit_cast(unsigned int, x);
  u += 0x7FFFu + ((u >> 16) & 1u);
  return (short)(u >> 16);
}
__device__ __forceinline__ float b2f(short s) {
  unsigned int u = ((unsigned int)(unsigned short)s) << 16;
  return __builtin_bit_cast(float, u);
}

__device__ __forceinline__ f32x4 mfma16(s8v a, s8v b, f32x4 c) {
  asm("v_mfma_f32_16x16x32_bf16 %0, %1, %2, %0" : "+v"(c) : "v"(a), "v"(b));
  return c;
}

// ---------------- exist-encoding detection ----------------
// codes: 0 = u8/bool, 1 = int32, 2 = float32, 3 = int64
__global__ __launch_bounds__(1024) void k_detect(const uint4* __restrict__ e0,
                                                 const uint4* __restrict__ e1,
                                                 int* __restrict__ flags) {
  __shared__ int red[3];
  int t = threadIdx.x;
  int arr = blockIdx.x;
  if (t < 3) red[t] = 0;
  __syncthreads();
  const uint4* p = arr ? e1 : e0;
  int mis = 0, gt = 0, od = 0;
  for (int i = t; i < 4608; i += 1024) {    // first 73728 bytes (10% density => plenty)
    uint4 v = p[i];
    unsigned any = v.x | v.y | v.z | v.w;
    if (any) {
      if (any & 0xFFFFFF00u) mis = 1;
      if (any & 0xFEFEFEFEu) gt = 1;
      if (v.y | v.w) od = 1;
    }
  }
  if (mis) atomicOr(&red[0], 1);
  if (gt) atomicOr(&red[1], 1);
  if (od) atomicOr(&red[2], 1);
  __syncthreads();
  if (t == 0) flags[arr] = red[0] ? (red[1] ? 2 : 0) : (red[2] ? 1 : 3);
}

__device__ __forceinline__ int get_exist(const void* p, int code, int idx) {
  switch (code) {
    case 0: return ((const unsigned char*)p)[idx] != 0;
    case 1: return ((const int*)p)[idx] != 0;
    case 2: return ((const float*)p)[idx] != 0.0f;
    default: return ((const long long*)p)[idx] != 0;
  }
}

// ---------------- merged transpose: edges (z=0..7) + Wr/Wz/Wh (z=8..10) ----------------
// src rows always have 512 f32 cols. dst[n][k] bf16, pitch = dstPitch.
__global__ __launch_bounds__(256) void k_tr_all(const float* __restrict__ edges,
                                                const float* __restrict__ Wr,
                                                const float* __restrict__ Wz,
                                                const float* __restrict__ Wh,
                                                short* __restrict__ edgesT,
                                                short* __restrict__ WT) {
  __shared__ float t[32][33];
  int z = blockIdx.z;
  const float* src;
  short* dst;
  int dstPitch;
  if (z < 8) {
    if (blockIdx.y >= 16) return;           // edges: 512 rows only
    src = edges + (size_t)z * DD * DD;
    dst = edgesT + (size_t)z * DD * DD;
    dstPitch = DD;
  } else {
    int w = z - 8;
    src = w == 0 ? Wr : (w == 1 ? Wz : Wh);
    dst = WT + (size_t)w * (512 * 1536);
    dstPitch = 1536;
  }
  int r0 = blockIdx.y * 32, c0 = blockIdx.x * 32;
  int row = threadIdx.x >> 3, c4 = (threadIdx.x & 7) * 4;
  float4 v = *(const float4*)(src + (size_t)(r0 + row) * DD + c0 + c4);
  t[row][c4] = v.x; t[row][c4 + 1] = v.y; t[row][c4 + 2] = v.z; t[row][c4 + 3] = v.w;
  __syncthreads();
  s4v o;
  o[0] = f2bf(t[c4 + 0][row]); o[1] = f2bf(t[c4 + 1][row]);
  o[2] = f2bf(t[c4 + 2][row]); o[3] = f2bf(t[c4 + 3][row]);
  *(s4v*)(dst + (size_t)(c0 + row) * dstPitch + r0 + c4) = o;
}

// ---------------- staging + MFMA tile helpers ----------------
// LDS tile: 64 rows x 64 bf16, pitch 72 (pad +8 => 2-way bank aliasing, free)
__device__ __forceinline__ void stage_f32(const float* __restrict__ src, int pitch,
                                          short* lds, int tid) {
  int row = tid >> 2, cc = (tid & 3) * 16;
  const float* p = src + (size_t)row * pitch + cc;
  float4 v0 = *(const float4*)p;
  float4 v1 = *(const float4*)(p + 4);
  float4 v2 = *(const float4*)(p + 8);
  float4 v3 = *(const float4*)(p + 12);
  s8v h0, h1;
  h0[0] = f2bf(v0.x); h0[1] = f2bf(v0.y); h0[2] = f2bf(v0.z); h0[3] = f2bf(v0.w);
  h0[4] = f2bf(v1.x); h0[5] = f2bf(v1.y); h0[6] = f2bf(v1.z); h0[7] = f2bf(v1.w);
  h1[0] = f2bf(v2.x); h1[1] = f2bf(v2.y); h1[2] = f2bf(v2.z); h1[3] = f2bf(v2.w);
  h1[4] = f2bf(v3.x); h1[5] = f2bf(v3.y); h1[6] = f2bf(v3.z); h1[7] = f2bf(v3.w);
  *(s8v*)&lds[row * 72 + cc] = h0;
  *(s8v*)&lds[row * 72 + cc + 8] = h1;
}

__device__ __forceinline__ void stage_bf(const short* __restrict__ src, int pitch,
                                         short* lds, int tid) {
  int row = tid >> 2, cc = (tid & 3) * 16;
  const short* p = src + (size_t)row * pitch + cc;
  s8v h0 = *(const s8v*)p;
  s8v h1 = *(const s8v*)(p + 8);
  *(s8v*)&lds[row * 72 + cc] = h0;
  *(s8v*)&lds[row * 72 + cc + 8] = h1;
}

__device__ __forceinline__ void mfma_tile(const short* As, const short* Bs,
                                          int wr, int wc, int l, f32x4 acc[2][2]) {
  int lr = l & 15, lg = l >> 4;
#pragma unroll
  for (int ks = 0; ks < 64; ks += 32) {
    s8v a0 = *(const s8v*)&As[(wr + lr) * 72 + ks + 8 * lg];
    s8v a1 = *(const s8v*)&As[(wr + 16 + lr) * 72 + ks + 8 * lg];
    s8v b0 = *(const s8v*)&Bs[(wc + lr) * 72 + ks + 8 * lg];
    s8v b1 = *(const s8v*)&Bs[(wc + 16 + lr) * 72 + ks + 8 * lg];
    acc[0][0] = mfma16(a0, b0, acc[0][0]);
    acc[0][1] = mfma16(a0, b1, acc[0][1]);
    acc[1][0] = mfma16(a1, b0, acc[1][0]);
    acc[1][1] = mfma16(a1, b1, acc[1][1]);
  }
}

// ---------------- GEMM: allmsgsH[de][m][n] = bf16(nodes[m][k] * edges[de][k][n]) ----------------
__global__ __launch_bounds__(256) void k_gemm_msgs(const float* __restrict__ nodes,
                                                   const short* __restrict__ edgesT,
                                                   short* __restrict__ C) {
  __shared__ __align__(16) short As[64 * 72];
  __shared__ __align__(16) short Bs[64 * 72];
  int tid = threadIdx.x;
  int row0 = blockIdx.y * 64;
  int col0 = blockIdx.x * 64;        // [0,4096)
  int de = col0 >> 9, h0 = col0 & 511;
  const short* Bsrc = edgesT + (size_t)de * DD * DD + (size_t)h0 * DD;
  const float* Asrc = nodes + (size_t)row0 * DD;
  int w = tid >> 6, l = tid & 63;
  int wr = (w >> 1) * 32, wc = (w & 1) * 32;
  f32x4 acc[2][2] = {};
  for (int k0 = 0; k0 < DD; k0 += 64) {
    stage_f32(Asrc + k0, DD, As, tid);
    stage_bf(Bsrc + k0, DD, Bs, tid);
    __syncthreads();
    mfma_tile(As, Bs, wr, wc, l, acc);
    __syncthreads();
  }
  asm volatile("s_nop 7\n\ts_nop 7");   // MFMA->VALU writeback hazard guard
  int lr = l & 15, lg4 = (l >> 4) * 4;
#pragma unroll
  for (int fi = 0; fi < 2; ++fi)
#pragma unroll
    for (int fj = 0; fj < 2; ++fj) {
      f32x4 v = acc[fi][fj];
#pragma unroll
      for (int r = 0; r < 4; ++r) {
        int row = row0 + wr + fi * 16 + lg4 + r;
        int col = h0 + wc + fj * 16 + lr;
        C[((size_t)(de * ROWS + row)) * DD + col] = f2bf(v[r]);
      }
    }
}

// ---------------- proj reductions (bf16 msgs . Wa[512:1024]) ----------------
__global__ __launch_bounds__(256) void k_proj(const short* __restrict__ allmsgsH,
                                              const float* __restrict__ Wa_in,
                                              const float* __restrict__ Wa_out,
                                              float* __restrict__ proj) {
  int w = blockIdx.x * 4 + (threadIdx.x >> 6);   // 0..6143
  int lane = threadIdx.x & 63;
  int dir = w / (EE * ROWS);
  int rem = w % (EE * ROWS);
  const short* src =
      allmsgsH + ((size_t)(dir * EE + rem / ROWS) * ROWS + rem % ROWS) * DD;
  const float* wa = (dir ? Wa_out : Wa_in) + DD;
  float acc = 0.f;
  for (int i = lane; i < DD; i += 64) acc = fmaf(b2f(src[i]), wa[i], acc);
#pragma unroll
  for (int off = 32; off; off >>= 1) acc += __shfl_xor(acc, off);
  if (lane == 0) proj[w] = acc;
}

// ---------------- attention (+ fused s1 dot + fused nodes->Acat copy) ----------------
__global__ __launch_bounds__(256) void k_attn(const short* __restrict__ allmsgsH,
                                              const float* __restrict__ proj,
                                              const int* __restrict__ adj_in,
                                              const int* __restrict__ adj_out,
                                              const void* exist_in,
                                              const void* exist_out,
                                              const int* __restrict__ fr,
                                              const float* __restrict__ nodes,
                                              const float* __restrict__ Wa_in,
                                              const float* __restrict__ ba_in,
                                              const float* __restrict__ Wa_out,
                                              const float* __restrict__ ba_out,
                                              short* __restrict__ AcatH) {
  __shared__ float s_w[NN];
  __shared__ int s_tj[NN];
  __shared__ int s_ex[NN];
  __shared__ float s_part[5];
  int blk = blockIdx.x;       // dir*768 + b*96 + i
  int dir = blk / ROWS;
  int row = blk % ROWS;
  int b = row / NN;
  const int* adj = dir ? adj_out : adj_in;
  const void* ex = dir ? exist_out : exist_in;
  int code = fr[dir];
  int t = threadIdx.x, wv = t >> 6, lane = t & 63;
  int h0 = t, h1 = t + 256;
  const float* wa = dir ? Wa_out : Wa_in;
  float nv0 = nodes[(size_t)row * DD + h0];
  float nv1 = nodes[(size_t)row * DD + h1];
  // fused nodes->Acat copy (once, via dir==0 blocks)
  if (dir == 0) {
    short* dn = AcatH + (size_t)row * 1536 + 1024;
    dn[h0] = f2bf(nv0);
    dn[h1] = f2bf(nv1);
  }
  // fused s1 = nodes_row . wa[0:512] (wave shuffle reduce, 1 barrier)
  float p = fmaf(nv0, wa[h0], nv1 * wa[h1]);
#pragma unroll
  for (int off = 32; off; off >>= 1) p += __shfl_xor(p, off);
  if (lane == 0) s_part[wv] = p;
  // neighbor metadata
  if (t < NN) {
    int idx = row * NN + t;
    s_ex[t] = get_exist(ex, code, idx);
    s_tj[t] = adj[idx];
  }
  __syncthreads();
  float s1v = s_part[0] + s_part[1] + s_part[2] + s_part[3] +
              (dir ? ba_out[0] : ba_in[0]);
  if (t < NN) {
    float sc = -1e9f;
    if (s_ex[t]) {
      float x = s1v + proj[dir * (EE * ROWS) + s_tj[t] * ROWS + b * NN + t];
      sc = x >= 0.f ? x : 0.2f * x;
    }
    s_w[t] = sc;
  }
  __syncthreads();
  // softmax over 96 slots, wave 0 only (shuffle reduces)
  if (t < 64) {
    float e1 = s_w[t];
    float e2 = (t < 32) ? s_w[t + 64] : -1e30f;
    float mx = fmaxf(e1, e2);
#pragma unroll
    for (int off = 32; off; off >>= 1) mx = fmaxf(mx, __shfl_xor(mx, off));
    float w1 = s_ex[t] ? __expf(e1 - mx) : 0.f;
    float w2 = (t < 32 && s_ex[t + 64]) ? __expf(e2 - mx) : 0.f;
    s_w[t] = w1;
    if (t < 32) s_w[t + 64] = w2;
    float sm = w1 + w2;
#pragma unroll
    for (int off = 32; off; off >>= 1) sm += __shfl_xor(sm, off);
    if (t == 0) s_part[4] = 1.f / sm;
  }
  __syncthreads();
  float inv = s_part[4];
  float acc0 = 0.f, acc1 = 0.f;
  for (int j = 0; j < NN; ++j) {
    if (s_ex[j]) {
      float wj = s_w[j];
      const short* rp =
          allmsgsH + ((size_t)(dir * EE + s_tj[j]) * ROWS + b * NN + j) * DD;
      acc0 = fmaf(wj, b2f(rp[h0]), acc0);
      acc1 = fmaf(wj, b2f(rp[h1]), acc1);
    }
  }
  short* dst = AcatH + (size_t)row * 1536 + dir * DD;
  dst[h0] = f2bf(acc0 * inv);
  dst[h1] = f2bf(acc1 * inv);
}

// ---------------- GEMM1: AcatH[768,1536] @ {WrT|WzT|WhT[:,:1024]} + epilogue ----------------
__global__ __launch_bounds__(256) void k_gemm1(const short* __restrict__ AcatH,
                                               const short* __restrict__ WT,
                                               const float* __restrict__ br,
                                               const float* __restrict__ bz,
                                               const float* __restrict__ nodes,
                                               short* __restrict__ rnH,
                                               float* __restrict__ zb,
                                               float* __restrict__ Hpre) {
  __shared__ __align__(16) short As[64 * 72];
  __shared__ __align__(16) short Bs[64 * 72];
  int tid = threadIdx.x;
  int row0 = blockIdx.y * 64;
  int col0 = blockIdx.x * 64;           // [0,1536)
  int region = col0 >> 9, c0 = col0 & 511;
  int K = (region == 2) ? 1024 : 1536;
  const short* Bsrc = WT + (size_t)region * (512 * 1536) + (size_t)c0 * 1536;
  const short* Asrc = AcatH + (size_t)row0 * 1536;
  int w = tid >> 6, l = tid & 63;
  int wr = (w >> 1) * 32, wc = (w & 1) * 32;
  f32x4 acc[2][2] = {};
  for (int k0 = 0; k0 < K; k0 += 64) {
    stage_bf(Asrc + k0, 1536, As, tid);
    stage_bf(Bsrc + k0, 1536, Bs, tid);
    __syncthreads();
    mfma_tile(As, Bs, wr, wc, l, acc);
    __syncthreads();
  }
  asm volatile("s_nop 7\n\ts_nop 7");
  int lr = l & 15, lg4 = (l >> 4) * 4;
#pragma unroll
  for (int fi = 0; fi < 2; ++fi)
#pragma unroll
    for (int fj = 0; fj < 2; ++fj) {
      f32x4 v = acc[fi][fj];
#pragma unroll
      for (int r = 0; r < 4; ++r) {
        int row = row0 + wr + fi * 16 + lg4 + r;
        int c = c0 + wc + fj * 16 + lr;
        float vv = v[r];
        size_t o = (size_t)row * DD + c;
        if (region == 0) {
          float s = 1.f / (1.f + __expf(-(vv + br[c])));
          rnH[o] = f2bf(s * nodes[o]);
        } else if (region == 1) {
          zb[o] = 1.f / (1.f + __expf(-(vv + bz[c])));
        } else {
          Hpre[o] = vv;
        }
      }
    }
}

// ---------------- GEMM2: rn @ WhT[:,1024:] + final gate ----------------
__global__ __launch_bounds__(256) void k_gemm2(const short* __restrict__ rnH,
                                               const short* __restrict__ WT,
                                               const float* __restrict__ bh,
                                               const float* __restrict__ Hpre,
                                               const float* __restrict__ zb,
                                               const float* __restrict__ nodes,
                                               float* __restrict__ out) {
  __shared__ __align__(16) short As[64 * 72];
  __shared__ __align__(16) short Bs[64 * 72];
  int tid = threadIdx.x;
  int row0 = blockIdx.y * 64;
  int col0 = blockIdx.x * 64;           // [0,512)
  const short* Bsrc = WT + (size_t)2 * (512 * 1536) + (size_t)col0 * 1536 + 1024;
  const short* Asrc = rnH + (size_t)row0 * DD;
  int w = tid >> 6, l = tid & 63;
  int wr = (w >> 1) * 32, wc = (w & 1) * 32;
  f32x4 acc[2][2] = {};
  for (int k0 = 0; k0 < DD; k0 += 64) {
    stage_bf(Asrc + k0, DD, As, tid);
    stage_bf(Bsrc + k0, 1536, Bs, tid);
    __syncthreads();
    mfma_tile(As, Bs, wr, wc, l, acc);
    __syncthreads();
  }
  asm volatile("s_nop 7\n\ts_nop 7");
  int lr = l & 15, lg4 = (l >> 4) * 4;
#pragma unroll
  for (int fi = 0; fi < 2; ++fi)
#pragma unroll
    for (int fj = 0; fj < 2; ++fj) {
      f32x4 v = acc[fi][fj];
#pragma unroll
      for (int r = 0; r < 4; ++r) {
        int row = row0 + wr + fi * 16 + lg4 + r;
        int c = col0 + wc + fj * 16 + lr;
        size_t o = (size_t)row * DD + c;
        float h = tanhf(v[r] + Hpre[o] + bh[c]);
        float zz = zb[o];
        float nd = nodes[o];
        out[o] = (1.f - zz) * nd + zz * h;
      }
    }
}

extern "C" void kernel_launch(void* const* d_in, const int* in_sizes, int n_in,
                              void* d_out, int out_size, void* d_ws, size_t ws_size,
                              hipStream_t stream) {
  const float* nodes = (const float*)d_in[0];
  const float* edges = (const float*)d_in[1];
  const int* adj_in = (const int*)d_in[2];
  const int* adj_out = (const int*)d_in[3];
  const void* exist_in = d_in[4];
  const void* exist_out = d_in[5];
  const float* Wa_in = (const float*)d_in[6];
  const float* ba_in = (const float*)d_in[7];
  const float* Wa_out = (const float*)d_in[8];
  const float* ba_out = (const float*)d_in[9];
  const float* Wr = (const float*)d_in[10];
  const float* br = (const float*)d_in[11];
  const float* Wz = (const float*)d_in[12];
  const float* bz = (const float*)d_in[13];
  const float* Wh = (const float*)d_in[14];
  const float* bh = (const float*)d_in[15];

  char* ws = (char*)d_ws;
  int* flags = (int*)ws;
  short* allmsgsH = (short*)(ws + WS_ALLMSGS);
  float* proj = (float*)(ws + WS_PROJ);
  short* AcatH = (short*)(ws + WS_ACAT);
  short* edgesT = (short*)(ws + WS_EDGEST);
  short* WT = (short*)(ws + WS_WT);
  short* rnH = (short*)(ws + WS_RN);
  float* zb = (float*)(ws + WS_ZB);
  float* Hpre = (float*)(ws + WS_HPRE);
  float* out = (float*)d_out;

  k_tr_all<<<dim3(16, 48, 11), 256, 0, stream>>>(edges, Wr, Wz, Wh, edgesT, WT);
  k_detect<<<2, 1024, 0, stream>>>((const uint4*)exist_in,
                                   (const uint4*)exist_out, flags);
  k_gemm_msgs<<<dim3(64, 12), 256, 0, stream>>>(nodes, edgesT, allmsgsH);
  k_proj<<<(2 * EE * ROWS) / 4, 256, 0, stream>>>(allmsgsH, Wa_in, Wa_out, proj);
  k_attn<<<2 * ROWS, 256, 0, stream>>>(allmsgsH, proj, adj_in, adj_out,
                                       exist_in, exist_out, flags, nodes,
                                       Wa_in, ba_in, Wa_out, ba_out, AcatH);
  k_gemm1<<<dim3(24, 12), 256, 0, stream>>>(AcatH, WT, br, bz, nodes, rnH, zb, Hpre);
  k_gemm2<<<dim3(8, 12), 256, 0, stream>>>(rnH, WT, bh, Hpre, zb, nodes, out);
}